// Round 1
// baseline (1107.523 us; speedup 1.0000x reference)
//
#include <hip/hip_runtime.h>
#include <math.h>

#define F_IN  128
#define F_OUT 64

// ---------------- degree via atomics ----------------
__global__ void k_deg(const int* __restrict__ dst, int E, float* __restrict__ deg) {
    int i = blockIdx.x * blockDim.x + threadIdx.x;
    int stride = gridDim.x * blockDim.x;
    for (int e = i; e < E; e += stride)
        atomicAdd(&deg[dst[e]], 1.0f);
}

// deg -> dinv = rsqrt(deg + 1)   (+1 = self loop; always > 0)
__global__ void k_dinv(float* __restrict__ deg, int N) {
    int i = blockIdx.x * blockDim.x + threadIdx.x;
    if (i < N) deg[i] = rsqrtf(deg[i] + 1.0f);
}

// ---------------- h = x @ W^T ; agg_init = h * dinv^2 (self loop) ----------------
// block = 256 threads: lane f = tid&63 (output feature), rg = tid>>6 (row group).
// Each block processes 64 rows in 4 chunks of 16; each thread owns 4 rows/chunk.
// W (64x128 fp32 = 32KB) lives in LDS, XOR-swizzled at float4 granularity so
// ds_read_b128 across lanes is conflict-free. x chunk (16x128 = 8KB) in LDS,
// read as wave-uniform broadcasts (conflict-free).
__global__ __launch_bounds__(256) void k_gemm(
    const float* __restrict__ x, const float* __restrict__ W,
    const float* __restrict__ dinv, float* __restrict__ h,
    float* __restrict__ agg, int N) {
    __shared__ float Ws[F_OUT * F_IN];   // swizzled, 32 KB
    __shared__ float xs[16 * F_IN];      // 8 KB

    const int tid = threadIdx.x;
    const int f   = tid & 63;
    const int rg  = tid >> 6;            // 0..3

    // load W with float4, swizzle quad index: q' = q ^ (f & 31)
    const float4* W4 = (const float4*)W;
    float4* Ws4 = (float4*)Ws;
    {
        int idx4 = tid;                  // 2048 quads total, 256 threads -> 8 each
        #pragma unroll
        for (int t = 0; t < 8; ++t, idx4 += 256) {
            int fr = idx4 >> 5;          // row (0..63)
            int q  = idx4 & 31;          // quad in row
            Ws4[fr * 32 + (q ^ (fr & 31))] = W4[idx4];
        }
    }

    const int row0 = blockIdx.x * 64;
    float4* xs4 = (float4*)xs;

    for (int c = 0; c < 4; ++c) {
        int rbase = row0 + c * 16;
        __syncthreads();                 // protect xs reuse
        // load 16 rows x 128 = 512 quads; 256 threads -> 2 each
        {
            const float4* x4 = (const float4*)x;
            int idx4 = tid;
            #pragma unroll
            for (int t = 0; t < 2; ++t, idx4 += 256) {
                int r  = idx4 >> 5;
                int cq = idx4 & 31;
                int grow = rbase + r;
                float4 v = make_float4(0.f, 0.f, 0.f, 0.f);
                if (grow < N) v = x4[(size_t)grow * 32 + cq];
                xs4[r * 32 + cq] = v;
            }
        }
        __syncthreads();

        float acc0 = 0.f, acc1 = 0.f, acc2 = 0.f, acc3 = 0.f;
        const int xbase = rg * 4;        // this thread's 4 rows within chunk
        #pragma unroll
        for (int q = 0; q < 32; ++q) {
            float4 w = Ws4[f * 32 + (q ^ (f & 31))];
            float4 a0 = xs4[(xbase + 0) * 32 + q];
            float4 a1 = xs4[(xbase + 1) * 32 + q];
            float4 a2 = xs4[(xbase + 2) * 32 + q];
            float4 a3 = xs4[(xbase + 3) * 32 + q];
            acc0 = fmaf(a0.x, w.x, fmaf(a0.y, w.y, fmaf(a0.z, w.z, fmaf(a0.w, w.w, acc0))));
            acc1 = fmaf(a1.x, w.x, fmaf(a1.y, w.y, fmaf(a1.z, w.z, fmaf(a1.w, w.w, acc1))));
            acc2 = fmaf(a2.x, w.x, fmaf(a2.y, w.y, fmaf(a2.z, w.z, fmaf(a2.w, w.w, acc2))));
            acc3 = fmaf(a3.x, w.x, fmaf(a3.y, w.y, fmaf(a3.z, w.z, fmaf(a3.w, w.w, acc3))));
        }

        float accs[4] = {acc0, acc1, acc2, acc3};
        #pragma unroll
        for (int r = 0; r < 4; ++r) {
            int row = rbase + xbase + r;
            if (row < N) {
                float d = dinv[row];
                size_t o = (size_t)row * F_OUT + f;
                h[o]   = accs[r];
                agg[o] = accs[r] * d * d;
            }
        }
    }
}

// ---------------- edge scatter: wave per edge, lane = feature ----------------
__global__ void k_scatter(const int* __restrict__ src, const int* __restrict__ dst,
                          const float* __restrict__ dinv, const float* __restrict__ h,
                          float* __restrict__ agg, int E) {
    int lane   = threadIdx.x & 63;
    int wave   = (blockIdx.x * blockDim.x + threadIdx.x) >> 6;
    int nwaves = (gridDim.x * blockDim.x) >> 6;
    for (int e = wave; e < E; e += nwaves) {
        int s = src[e], d = dst[e];
        float norm = dinv[s] * dinv[d];
        float v = h[(size_t)s * F_OUT + lane] * norm;
        atomicAdd(&agg[(size_t)d * F_OUT + lane], v);
    }
}

// ---------------- epilogue: relu(agg+b) . W_lin + b_lin -> sigmoid ----------------
__global__ void k_final(const float* __restrict__ agg, const float* __restrict__ b_conv,
                        const float* __restrict__ W_lin, const float* __restrict__ b_lin,
                        float* __restrict__ out, int N) {
    int lane   = threadIdx.x & 63;
    int wave   = (blockIdx.x * blockDim.x + threadIdx.x) >> 6;
    int nwaves = (gridDim.x * blockDim.x) >> 6;
    float w  = W_lin[lane];
    float b  = b_conv[lane];
    float bl = b_lin[0];
    for (int i = wave; i < N; i += nwaves) {
        float a = agg[(size_t)i * F_OUT + lane] + b;
        a = fmaxf(a, 0.f);
        float t = a * w;
        #pragma unroll
        for (int off = 32; off > 0; off >>= 1)
            t += __shfl_down(t, off, 64);
        if (lane == 0)
            out[i] = 1.0f / (1.0f + expf(-(t + bl)));
    }
}

extern "C" void kernel_launch(void* const* d_in, const int* in_sizes, int n_in,
                              void* d_out, int out_size, void* d_ws, size_t ws_size,
                              hipStream_t stream) {
    const float* x      = (const float*)d_in[0];
    const int*   ei     = (const int*)d_in[1];
    const float* W_conv = (const float*)d_in[2];
    const float* b_conv = (const float*)d_in[3];
    const float* W_lin  = (const float*)d_in[4];
    const float* b_lin  = (const float*)d_in[5];

    const int N = in_sizes[0] / F_IN;     // 100000
    const int E = in_sizes[1] / 2;        // 1600000
    const int* src = ei;
    const int* dst = ei + E;
    float* out = (float*)d_out;

    // workspace layout (fp32): deg/dinv [N] | h [N*64] | agg [N*64]
    float* deg = (float*)d_ws;
    float* h   = deg + ((N + 255) & ~255);
    float* agg = h + (size_t)N * F_OUT;

    hipMemsetAsync(deg, 0, sizeof(float) * N, stream);
    k_deg<<<2048, 256, 0, stream>>>(dst, E, deg);
    k_dinv<<<(N + 255) / 256, 256, 0, stream>>>(deg, N);
    k_gemm<<<(N + 63) / 64, 256, 0, stream>>>(x, W_conv, deg, h, agg, N);
    k_scatter<<<8192, 256, 0, stream>>>(src, dst, deg, h, agg, E);
    k_final<<<4096, 256, 0, stream>>>(agg, b_conv, W_lin, b_lin, out, N);
}

// Round 2
// 398.463 us; speedup vs baseline: 2.7795x; 2.7795x over previous
//
#include <hip/hip_runtime.h>
#include <math.h>

#define F_IN  128
#define F_OUT 64

// ---------------- in-degree histogram (int) ----------------
__global__ void k_count(const int* __restrict__ dst, int E, int* __restrict__ cnt) {
    int i = blockIdx.x * blockDim.x + threadIdx.x;
    int stride = gridDim.x * blockDim.x;
    for (int e = i; e < E; e += stride)
        atomicAdd(&cnt[dst[e]], 1);
}

// dinv = rsqrt(cnt + 1)   (+1 = self loop)
__global__ void k_dinv(const int* __restrict__ cnt, float* __restrict__ dinv, int N) {
    int i = blockIdx.x * blockDim.x + threadIdx.x;
    if (i < N) dinv[i] = rsqrtf((float)cnt[i] + 1.0f);
}

// ---------------- 3-phase exclusive scan of cnt -> offsets ----------------
__global__ void k_scan1(const int* __restrict__ cnt, int* __restrict__ tmp,
                        int* __restrict__ bsum, int N) {
    __shared__ int sh[256];
    int i = blockIdx.x * 256 + threadIdx.x;
    int v = (i < N) ? cnt[i] : 0;
    sh[threadIdx.x] = v;
    __syncthreads();
    for (int off = 1; off < 256; off <<= 1) {
        int t = (threadIdx.x >= off) ? sh[threadIdx.x - off] : 0;
        __syncthreads();
        sh[threadIdx.x] += t;
        __syncthreads();
    }
    if (i < N) tmp[i] = sh[threadIdx.x];           // inclusive within block
    if (threadIdx.x == 255) bsum[blockIdx.x] = sh[255];
}

__global__ void k_scan2(int* __restrict__ bsum, int NB) {
    __shared__ int sh[512];
    int v = (threadIdx.x < NB) ? bsum[threadIdx.x] : 0;
    sh[threadIdx.x] = v;
    __syncthreads();
    for (int off = 1; off < 512; off <<= 1) {
        int t = (threadIdx.x >= off) ? sh[threadIdx.x - off] : 0;
        __syncthreads();
        sh[threadIdx.x] += t;
        __syncthreads();
    }
    if (threadIdx.x < NB) bsum[threadIdx.x] = sh[threadIdx.x] - v;  // exclusive
}

__global__ void k_scan3(const int* __restrict__ cnt, const int* __restrict__ tmp,
                        const int* __restrict__ bsum, int* __restrict__ offsets,
                        int* __restrict__ cursor, int N, int E) {
    int i = blockIdx.x * 256 + threadIdx.x;
    if (i < N) {
        int o = tmp[i] - cnt[i] + bsum[blockIdx.x];  // exclusive offset
        offsets[i] = o;
        cursor[i]  = o;
    }
    if (i == 0) offsets[N] = E;
}

// ---------------- bucket edges by dst: srcs sorted by dst ----------------
__global__ void k_bucket(const int* __restrict__ src, const int* __restrict__ dst,
                         int* __restrict__ cursor, int* __restrict__ srcs, int E) {
    int i = blockIdx.x * blockDim.x + threadIdx.x;
    int stride = gridDim.x * blockDim.x;
    for (int e = i; e < E; e += stride) {
        int d = dst[e];
        int pos = atomicAdd(&cursor[d], 1);
        srcs[pos] = src[e];
    }
}

// ---------------- g = (x @ W^T) * dinv[row] ----------------
__global__ __launch_bounds__(256) void k_gemm(
    const float* __restrict__ x, const float* __restrict__ W,
    const float* __restrict__ dinv, float* __restrict__ g, int N) {
    __shared__ float Ws[F_OUT * F_IN];   // swizzled, 32 KB
    __shared__ float xs[16 * F_IN];      // 8 KB

    const int tid = threadIdx.x;
    const int f   = tid & 63;
    const int rg  = tid >> 6;

    const float4* W4 = (const float4*)W;
    float4* Ws4 = (float4*)Ws;
    {
        int idx4 = tid;
        #pragma unroll
        for (int t = 0; t < 8; ++t, idx4 += 256) {
            int fr = idx4 >> 5;
            int q  = idx4 & 31;
            Ws4[fr * 32 + (q ^ (fr & 31))] = W4[idx4];
        }
    }

    const int row0 = blockIdx.x * 64;
    float4* xs4 = (float4*)xs;

    for (int c = 0; c < 4; ++c) {
        int rbase = row0 + c * 16;
        __syncthreads();
        {
            const float4* x4 = (const float4*)x;
            int idx4 = tid;
            #pragma unroll
            for (int t = 0; t < 2; ++t, idx4 += 256) {
                int r  = idx4 >> 5;
                int cq = idx4 & 31;
                int grow = rbase + r;
                float4 v = make_float4(0.f, 0.f, 0.f, 0.f);
                if (grow < N) v = x4[(size_t)grow * 32 + cq];
                xs4[r * 32 + cq] = v;
            }
        }
        __syncthreads();

        float acc0 = 0.f, acc1 = 0.f, acc2 = 0.f, acc3 = 0.f;
        const int xbase = rg * 4;
        #pragma unroll 4
        for (int q = 0; q < 32; ++q) {
            float4 w = Ws4[f * 32 + (q ^ (f & 31))];
            float4 a0 = xs4[(xbase + 0) * 32 + q];
            float4 a1 = xs4[(xbase + 1) * 32 + q];
            float4 a2 = xs4[(xbase + 2) * 32 + q];
            float4 a3 = xs4[(xbase + 3) * 32 + q];
            acc0 = fmaf(a0.x, w.x, fmaf(a0.y, w.y, fmaf(a0.z, w.z, fmaf(a0.w, w.w, acc0))));
            acc1 = fmaf(a1.x, w.x, fmaf(a1.y, w.y, fmaf(a1.z, w.z, fmaf(a1.w, w.w, acc1))));
            acc2 = fmaf(a2.x, w.x, fmaf(a2.y, w.y, fmaf(a2.z, w.z, fmaf(a2.w, w.w, acc2))));
            acc3 = fmaf(a3.x, w.x, fmaf(a3.y, w.y, fmaf(a3.z, w.z, fmaf(a3.w, w.w, acc3))));
        }

        float accs[4] = {acc0, acc1, acc2, acc3};
        #pragma unroll
        for (int r = 0; r < 4; ++r) {
            int row = rbase + xbase + r;
            if (row < N) {
                float d = dinv[row];
                g[(size_t)row * F_OUT + f] = accs[r] * d;
            }
        }
    }
}

// ---------------- pull aggregation + fused epilogue ----------------
// wave per node, lane = feature.
// agg = dinv[i] * (g[i] + sum_{e in-edges} g[srcs[e]])
// out[i] = sigmoid( dot(relu(agg + b_conv), W_lin) + b_lin )
__global__ __launch_bounds__(256) void k_pull(
    const float* __restrict__ g, const int* __restrict__ offsets,
    const int* __restrict__ srcs, const float* __restrict__ dinv,
    const float* __restrict__ b_conv, const float* __restrict__ W_lin,
    const float* __restrict__ b_lin, float* __restrict__ out, int N) {
    const int lane   = threadIdx.x & 63;
    const int wave   = (blockIdx.x * blockDim.x + threadIdx.x) >> 6;
    const int nwaves = (gridDim.x * blockDim.x) >> 6;
    const float wl = W_lin[lane];
    const float b  = b_conv[lane];
    const float bl = b_lin[0];

    for (int i = wave; i < N; i += nwaves) {
        float acc = g[(size_t)i * F_OUT + lane];   // self loop
        int e0 = offsets[i], e1 = offsets[i + 1];
        int e = e0;
        for (; e + 4 <= e1; e += 4) {
            int s0 = srcs[e], s1 = srcs[e + 1], s2 = srcs[e + 2], s3 = srcs[e + 3];
            float v0 = g[(size_t)s0 * F_OUT + lane];
            float v1 = g[(size_t)s1 * F_OUT + lane];
            float v2 = g[(size_t)s2 * F_OUT + lane];
            float v3 = g[(size_t)s3 * F_OUT + lane];
            acc += v0 + v1 + v2 + v3;
        }
        for (; e < e1; ++e)
            acc += g[(size_t)srcs[e] * F_OUT + lane];

        float a = fmaxf(acc * dinv[i] + b, 0.f);
        float t = a * wl;
        #pragma unroll
        for (int off = 32; off > 0; off >>= 1)
            t += __shfl_down(t, off, 64);
        if (lane == 0)
            out[i] = 1.0f / (1.0f + expf(-(t + bl)));
    }
}

extern "C" void kernel_launch(void* const* d_in, const int* in_sizes, int n_in,
                              void* d_out, int out_size, void* d_ws, size_t ws_size,
                              hipStream_t stream) {
    const float* x      = (const float*)d_in[0];
    const int*   ei     = (const int*)d_in[1];
    const float* W_conv = (const float*)d_in[2];
    const float* b_conv = (const float*)d_in[3];
    const float* W_lin  = (const float*)d_in[4];
    const float* b_lin  = (const float*)d_in[5];

    const int N = in_sizes[0] / F_IN;     // 100000
    const int E = in_sizes[1] / 2;        // 1600000
    const int* src = ei;
    const int* dst = ei + E;
    float* out = (float*)d_out;

    const int NB = (N + 255) / 256;       // scan blocks (<= 512)
    const int Na = (N + 256) & ~255;      // padded N+1

    // workspace layout (4-byte units)
    int*   cnt     = (int*)d_ws;          // [Na]
    float* dinv    = (float*)(cnt + Na);  // [Na]
    int*   tmp     = (int*)(dinv + Na);   // [Na]
    int*   bsum    = tmp + Na;            // [512]
    int*   offsets = bsum + 512;          // [Na] (holds N+1)
    int*   cursor  = offsets + Na;        // [Na]
    int*   srcs    = cursor + Na;         // [E]
    float* g       = (float*)(srcs + ((E + 255) & ~255)); // [N*64]

    hipMemsetAsync(cnt, 0, sizeof(int) * N, stream);
    k_count<<<2048, 256, 0, stream>>>(dst, E, cnt);
    k_dinv<<<NB, 256, 0, stream>>>(cnt, dinv, N);
    k_scan1<<<NB, 256, 0, stream>>>(cnt, tmp, bsum, N);
    k_scan2<<<1, 512, 0, stream>>>(bsum, NB);
    k_scan3<<<NB, 256, 0, stream>>>(cnt, tmp, bsum, offsets, cursor, N, E);
    k_bucket<<<2048, 256, 0, stream>>>(src, dst, cursor, srcs, E);
    k_gemm<<<(N + 63) / 64, 256, 0, stream>>>(x, W_conv, dinv, g, N);
    k_pull<<<2048, 256, 0, stream>>>(g, offsets, srcs, dinv, b_conv, W_lin, b_lin, out, N);
}